// Round 9
// baseline (214.034 us; speedup 1.0000x reference)
//
#include <hip/hip_runtime.h>
#include <hip/hip_fp16.h>
#include <math.h>

// Problem constants (from reference)
constexpr int N_NODES = 100000;
constexpr int N_EDGES = 3200000;
constexpr int NF      = 6;

// R9: TLP fix.  R5-R8 evidence chain:
//   - accum time == Little's-law latency model (VMEM concurrency ~4/wave,
//     ~350cy L2): 16 waves/CU -> 52us.  Measured 51-56us every round.
//   - R6/R7/R8 tried to raise per-wave ILP (deep load queue); compiler
//     refused 3x (VGPR pinned at 28; liveness can't be forced by ordering
//     tools).  So raise WAVES instead: NB=512 buckets (~195 nodes, ~6250
//     records), 512 x 1024-thread blocks -> 2 co-resident blocks/CU
//     (2048 thr = HW max, 32 waves/CU) -> 2x VMEM in flight -> ~halved time.
// Bucket id: b = floor(row*512/100000) = (row<<9)*351843721 >> 45 (exact,
// valid x < 3.1e9; max x = 51.2e6).  base(b) = (b*100000+511)>>9.
// nodes/bucket in {195,196} -> li fits 8 bits (record: col|li<<17, half2).
constexpr int NB      = 512;
constexpr int NMAXB   = 196;                 // max nodes per bucket
constexpr int CAP     = 7168;                // 7*1024; mean 6250 + 11.6 sigma
constexpr int KREC    = CAP / 1024;          // 7 records per accum thread
constexpr int TILE    = 2048;                // edges per partition block
constexpr int EPT     = TILE / 256;          // 8 edges per thread (contiguous group)
constexpr int NBLK_PART = (N_EDGES + TILE - 1) / TILE;     // 1563
constexpr int VPREP_BLOCKS = (N_NODES + 255) / 256;        // 391

__device__ __forceinline__ unsigned bucket_of(int r) {
    // floor(r*512/100000), exact (see header comment)
    return (unsigned)(((unsigned long long)((unsigned)r << 9) * 351843721ull) >> 45);
}
__device__ __forceinline__ int base_of(unsigned b) {
    return (int)((b * 100000u + 511u) >> 9);
}

// ---------------- ws layout (bytes) ----------------
constexpr size_t OFF_V    = 0;                                // float2[N_NODES]
constexpr size_t OFF_REC  = OFF_V + (size_t)N_NODES * 8;      // 800,000
constexpr size_t OFF_CNT  = OFF_REC + (size_t)NB * CAP * 8;   // +29,360,128
// counter block (zeroed by 4KB hipMemsetAsync):
//   gcur[512] at +0 (2048B), sums[3] at +2048, done_all at +2064
constexpr size_t WS_NEED  = OFF_CNT + 4096;   // ~30.2 MB (< proven-safe 42.85 MB)

__device__ __forceinline__ float2 half2u_to_f2(unsigned u) {
    __half2 h;
    *reinterpret_cast<unsigned*>(&h) = u;
    return __half22float2(h);
}

// Bucket-sort edges through LDS into per-bucket record chunks.
// R9 plumbing for NB=512: ONE shared histogram/cursor (within-bucket order
// is irrelevant for a sum) -> LDS ~28.7KB (was 33.3KB at NB=256 per-wave),
// preserving partition residency.  Pair-per-thread shfl scan (512 buckets,
// 256 threads).  Folds node_prep (V = Vm*e^{iVa}) into the first 391 blocks.
__global__ __launch_bounds__(256) void partition_edges(
        const int* __restrict__ row, const int* __restrict__ col,
        const float2* __restrict__ attr,
        const float* __restrict__ pred, const float* __restrict__ target,
        const unsigned char* __restrict__ mask,
        float2* __restrict__ v_out,
        unsigned int* __restrict__ gcur,
        uint2* __restrict__ rec_g) {
    __shared__ unsigned int h[NB];          // shared histogram (2 KB)
    __shared__ unsigned int cur[NB];        // shared placement cursor (2 KB)
    __shared__ int sbase[NB];               // local exclusive base (2 KB)
    __shared__ int dbase[NB];               // global_base - local_base (2 KB)
    __shared__ unsigned int wsum_s[4];      // per-wave scan totals
    __shared__ uint2 rec_s[TILE];           // staged records (bucket-sorted), 16 KB
    __shared__ unsigned short bkt_s[TILE];  // staged bucket id (4 KB)
    __shared__ int total_s;

    const int tid = threadIdx.x;
    const int w = tid >> 6;
    const int e0 = blockIdx.x * TILE;
    const int e_base = e0 + tid * EPT;          // 8 contiguous edges per thread
    const bool ok = e_base < N_EDGES;           // N_EDGES % 8 == 0: whole group valid/invalid

    // folded node_prep (no LDS use; overlaps with everything)
    if (blockIdx.x < VPREP_BLOCKS) {
        int i = blockIdx.x * 256 + tid;
        if (i < N_NODES) {
            const int bb = i * NF;
            float vm = mask[bb + 0] ? pred[bb + 0] : target[bb + 0];
            float va = mask[bb + 1] ? pred[bb + 1] : target[bb + 1];
            float sn, cs;
            sincosf(va, &sn, &cs);
            v_out[i] = make_float2(vm * cs, vm * sn);
        }
    }

    // zero histogram + cursor (512+512 entries over 256 threads)
    h[tid] = 0u;  h[tid + 256] = 0u;
    cur[tid] = 0u; cur[tid + 256] = 0u;
    __syncthreads();

    // Phase 1: vectorized row loads (2 x int4) + shared LDS histogram
    int r[EPT];
    unsigned bk[EPT];
    if (ok) {
        int4 ra = *(const int4*)(row + e_base);
        int4 rb = *(const int4*)(row + e_base + 4);
        r[0]=ra.x; r[1]=ra.y; r[2]=ra.z; r[3]=ra.w;
        r[4]=rb.x; r[5]=rb.y; r[6]=rb.z; r[7]=rb.w;
        #pragma unroll
        for (int k = 0; k < EPT; ++k) {
            bk[k] = bucket_of(r[k]);
            atomicAdd(&h[bk[k]], 1u);
        }
    }
    __syncthreads();

    // Phase 2+3: pair-per-thread exclusive scan (thread tid owns buckets
    // 2tid, 2tid+1) + global chunk reservation.
    {
        int b0 = 2 * tid, b1 = 2 * tid + 1;
        unsigned c0 = h[b0], c1 = h[b1];
        unsigned pair = c0 + c1;
        unsigned incl = pair;
        #pragma unroll
        for (int off = 1; off < 64; off <<= 1) {
            unsigned n = __shfl_up(incl, off, 64);
            if ((tid & 63) >= off) incl += n;
        }
        if ((tid & 63) == 63) wsum_s[w] = incl;
        __syncthreads();
        unsigned woff = 0;
        if (w > 0) woff += wsum_s[0];
        if (w > 1) woff += wsum_s[1];
        if (w > 2) woff += wsum_s[2];
        unsigned excl = woff + incl - pair;        // exclusive base of b0
        sbase[b0] = (int)excl;
        sbase[b1] = (int)(excl + c0);
        unsigned g0 = c0 ? atomicAdd(&gcur[b0], c0) : 0u;
        unsigned g1 = c1 ? atomicAdd(&gcur[b1], c1) : 0u;
        dbase[b0] = (int)g0 - (int)excl;
        dbase[b1] = (int)g1 - (int)(excl + c0);
        if (tid == 255) total_s = (int)(woff + incl);
    }
    __syncthreads();

    // Phase 4: pack records (col|li<<17, half2 attr), place into sorted LDS slots
    if (ok) {
        int4 ca = *(const int4*)(col + e_base);
        int4 cb = *(const int4*)(col + e_base + 4);
        int c[EPT] = {ca.x, ca.y, ca.z, ca.w, cb.x, cb.y, cb.z, cb.w};
        float4 a0 = *(const float4*)(attr + e_base);      // edges 0,1
        float4 a1 = *(const float4*)(attr + e_base + 2);  // edges 2,3
        float4 a2 = *(const float4*)(attr + e_base + 4);  // edges 4,5
        float4 a3 = *(const float4*)(attr + e_base + 6);  // edges 6,7
        float gx[EPT] = {a0.x, a0.z, a1.x, a1.z, a2.x, a2.z, a3.x, a3.z};
        float gy[EPT] = {a0.y, a0.w, a1.y, a1.w, a2.y, a2.w, a3.y, a3.w};
        #pragma unroll
        for (int k = 0; k < EPT; ++k) {
            unsigned b = bk[k];
            unsigned li = (unsigned)(r[k] - base_of(b));   // <= 195, fits 8 bits
            int slot = sbase[b] + (int)atomicAdd(&cur[b], 1u);
            __half2 hh = __floats2half2_rn(gx[k], gy[k]);
            rec_s[slot] = make_uint2((unsigned)c[k] | (li << 17),
                                     *reinterpret_cast<unsigned int*>(&hh));
            bkt_s[slot] = (unsigned short)b;
        }
    }
    __syncthreads();

    // Phase 5: coalesced flush in slot order (one dwordx2 store per record)
    const int total = total_s;
    for (int j = tid; j < total; j += 256) {
        int b = (int)bkt_s[j];
        int g = dbase[b] + j;
        if (g < CAP)
            rec_g[(size_t)b * CAP + g] = rec_s[j];
    }
}

// One 1024-thread block per bucket; 512 blocks -> 2 co-resident blocks/CU
// (32 waves/CU, 2x the VMEM concurrency of R5-R8).  Thread tid owns records
// {tid + k*1024, k<7}: unconditional record loads, masked gathers, masked
// LDS atomics.  Finalize straight from LDS (thread tid owns node base+tid).
// Global atomics: 3 returned adds + 1 done-counter per block — nothing else.
__global__ __launch_bounds__(1024) void accum_bucket(
        const unsigned int* __restrict__ gcur,
        const uint2* __restrict__ rec,
        const float2* __restrict__ v,
        const float* __restrict__ pred,
        const float* __restrict__ target,
        const unsigned char* __restrict__ mask,
        float* __restrict__ sums,
        unsigned int* __restrict__ done_all,
        float* __restrict__ out) {
    __shared__ float acc_re[NMAXB];
    __shared__ float acc_im[NMAXB];
    const int tid = threadIdx.x;
    const int b = blockIdx.x;
    const int cnt = (int)min(gcur[b], (unsigned)CAP);
    if (tid < NMAXB) { acc_re[tid] = 0.f; acc_im[tid] = 0.f; }
    __syncthreads();
    const uint2* rp = rec + (size_t)b * CAP;

    // unconditional record loads (index < CAP always), masked gathers
    uint2 q[KREC];
    #pragma unroll
    for (int k = 0; k < KREC; ++k)
        q[k] = rp[tid + (k << 10)];
    float2 vv[KREC];
    #pragma unroll
    for (int k = 0; k < KREC; ++k) {
        int idx = tid + (k << 10);
        unsigned c = (idx < cnt) ? (q[k].x & 0x1FFFFu) : 0u;
        vv[k] = v[c];
    }
    #pragma unroll
    for (int k = 0; k < KREC; ++k) {
        int idx = tid + (k << 10);
        if (idx < cnt) {
            int li = (int)(q[k].x >> 17);
            float2 gb = half2u_to_f2(q[k].y);
            float2 vk = vv[k];
            // (G - iB) * conj(V) = (G*vr - B*vi) + i*(-(G*vi + B*vr))
            atomicAdd(&acc_re[li], fmaf(gb.x, vk.x, -gb.y * vk.y));
            atomicAdd(&acc_im[li], -fmaf(gb.x, vk.y, gb.y * vk.x));
        }
    }
    __syncthreads();

    // ---- finalize straight from LDS: thread tid owns node base+tid ----
    const int base = base_of((unsigned)b);
    const int nb_nodes = base_of((unsigned)b + 1) - base;   // 195 or 196
    float a = 0.f, ar = 0.f, ai = 0.f;
    if (tid < nb_nodes) {
        int i = base + tid;
        float mr = acc_re[tid];
        float mi = acc_im[tid];
        const int bb = i * NF;
        uchar2 m23 = *(const uchar2*)(mask + bb + 2);   // 6i+2 even -> 2-aligned
        uchar2 m45 = *(const uchar2*)(mask + bb + 4);
        float2 p23 = *(const float2*)(pred + bb + 2);   // byte 24i+8  -> 8-aligned
        float2 p45 = *(const float2*)(pred + bb + 4);   // byte 24i+16 -> 8-aligned
        float2 t23 = *(const float2*)(target + bb + 2);
        float2 t45 = *(const float2*)(target + bb + 4);
        float pg = m23.x ? p23.x : t23.x;
        float qg = m23.y ? p23.y : t23.y;
        float pd = m45.x ? p45.x : t45.x;
        float qd = m45.y ? p45.y : t45.y;
        float2 vv2 = v[i];
        float s_re = vv2.x * mr - vv2.y * mi;
        float s_im = vv2.x * mi + vv2.y * mr;
        float dre = (pg - pd) - s_re;
        float dim = (qg - qd) - s_im;
        ar = fabsf(dre);
        ai = fabsf(dim);
        a  = sqrtf(dre * dre + dim * dim);
    }
    #pragma unroll
    for (int off = 32; off > 0; off >>= 1) {
        a  += __shfl_down(a,  off, 64);
        ar += __shfl_down(ar, off, 64);
        ai += __shfl_down(ai, off, 64);
    }
    __shared__ float red[3][16];
    int wave = tid >> 6;
    int lane = tid & 63;
    if (lane == 0) { red[0][wave] = a; red[1][wave] = ar; red[2][wave] = ai; }
    __syncthreads();
    if (tid == 0) {
        float s0 = 0.f, s1 = 0.f, s2 = 0.f;
        #pragma unroll
        for (int k = 0; k < 16; ++k) { s0 += red[0][k]; s1 += red[1][k]; s2 += red[2][k]; }
        // returned atomics: data dependency guarantees visibility before done_all
        float r0 = atomicAdd(&sums[0], s0);
        float r1 = atomicAdd(&sums[1], s1);
        float r2 = atomicAdd(&sums[2], s2);
        float chk = r0 + r1 + r2;
        if (chk == chk) {
            unsigned fin = atomicAdd(done_all, 1u);
            if (fin == (unsigned)(NB - 1)) {
                const float inv = 1.0f / (float)N_NODES;
                float t0 = atomicAdd(&sums[0], 0.f);   // coherent readback
                float t1 = atomicAdd(&sums[1], 0.f);
                float t2 = atomicAdd(&sums[2], 0.f);
                __hip_atomic_store(&out[0], t0 * inv, __ATOMIC_RELAXED, __HIP_MEMORY_SCOPE_AGENT);
                __hip_atomic_store(&out[1], t1 * inv, __ATOMIC_RELAXED, __HIP_MEMORY_SCOPE_AGENT);
                __hip_atomic_store(&out[2], t2 * inv, __ATOMIC_RELAXED, __HIP_MEMORY_SCOPE_AGENT);
            }
        }
    }
}

// ---------------- fallback (plain atomic path, if ws too small) ------------
__global__ void node_prep_fb(const float* __restrict__ pred,
                             const float* __restrict__ target,
                             const unsigned char* __restrict__ mask,
                             float2* __restrict__ v) {
    int i = blockIdx.x * blockDim.x + threadIdx.x;
    if (i >= N_NODES) return;
    const int b = i * NF;
    float vm = mask[b + 0] ? pred[b + 0] : target[b + 0];
    float va = mask[b + 1] ? pred[b + 1] : target[b + 1];
    float s, c;
    sincosf(va, &s, &c);
    v[i] = make_float2(vm * c, vm * s);
}

__global__ void edge_scatter_fb(const int* __restrict__ row,
                                const int* __restrict__ col,
                                const float2* __restrict__ attr,
                                const float2* __restrict__ v,
                                float2* __restrict__ mv) {
    int e = blockIdx.x * blockDim.x + threadIdx.x;
    if (e >= N_EDGES) return;
    int r = row[e];
    int c = col[e];
    float2 gb = attr[e];
    float2 vv = v[c];
    float mre = fmaf(gb.x, vv.x, -gb.y * vv.y);
    float mim = -fmaf(gb.x, vv.y, gb.y * vv.x);
    atomicAdd(&mv[r].x, mre);
    atomicAdd(&mv[r].y, mim);
}

__global__ void finalize_fb(const float* __restrict__ pred,
                            const float* __restrict__ target,
                            const unsigned char* __restrict__ mask,
                            const float2* __restrict__ v,
                            const float2* __restrict__ mv,
                            float* __restrict__ sums) {
    int i = blockIdx.x * blockDim.x + threadIdx.x;
    float a = 0.f, ar = 0.f, ai = 0.f;
    if (i < N_NODES) {
        const int b = i * NF;
        float pg = mask[b + 2] ? pred[b + 2] : target[b + 2];
        float qg = mask[b + 3] ? pred[b + 3] : target[b + 3];
        float pd = mask[b + 4] ? pred[b + 4] : target[b + 4];
        float qd = mask[b + 5] ? pred[b + 5] : target[b + 5];
        float netP = pg - pd;
        float netQ = qg - qd;
        float2 vv = v[i];
        float2 m = mv[i];
        float s_re = vv.x * m.x - vv.y * m.y;
        float s_im = vv.x * m.y + vv.y * m.x;
        float dre = netP - s_re;
        float dim = netQ - s_im;
        ar = fabsf(dre);
        ai = fabsf(dim);
        a  = sqrtf(dre * dre + dim * dim);
    }
    #pragma unroll
    for (int off = 32; off > 0; off >>= 1) {
        a  += __shfl_down(a,  off, 64);
        ar += __shfl_down(ar, off, 64);
        ai += __shfl_down(ai, off, 64);
    }
    __shared__ float red[3][4];
    int wave = threadIdx.x >> 6;
    int lane = threadIdx.x & 63;
    if (lane == 0) { red[0][wave] = a; red[1][wave] = ar; red[2][wave] = ai; }
    __syncthreads();
    if (threadIdx.x == 0) {
        atomicAdd(&sums[0], red[0][0] + red[0][1] + red[0][2] + red[0][3]);
        atomicAdd(&sums[1], red[1][0] + red[1][1] + red[1][2] + red[1][3]);
        atomicAdd(&sums[2], red[2][0] + red[2][1] + red[2][2] + red[2][3]);
    }
}

__global__ void write_out_fb(const float* __restrict__ sums, float* __restrict__ out) {
    if (threadIdx.x == 0 && blockIdx.x == 0) {
        const float inv = 1.0f / (float)N_NODES;
        out[0] = sums[0] * inv;
        out[1] = sums[1] * inv;
        out[2] = sums[2] * inv;
    }
}

extern "C" void kernel_launch(void* const* d_in, const int* in_sizes, int n_in,
                              void* d_out, int out_size, void* d_ws, size_t ws_size,
                              hipStream_t stream) {
    const float*         pred   = (const float*)d_in[0];
    const float*         target = (const float*)d_in[1];
    const int*           eidx   = (const int*)d_in[2];      // (2, N_EDGES)
    const float2*        attr   = (const float2*)d_in[3];   // (N_EDGES, 2)
    const unsigned char* mask   = (const unsigned char*)d_in[4];
    float* out = (float*)d_out;

    const int* row = eidx;             // edge_index[0] = src
    const int* col = eidx + N_EDGES;   // edge_index[1] = dst

    char* ws = (char*)d_ws;
    const int B = 256;

    if (ws_size >= WS_NEED) {
        float2*       v        = (float2*)(ws + OFF_V);
        uint2*        rec_g    = (uint2*)(ws + OFF_REC);
        unsigned int* gcur     = (unsigned int*)(ws + OFF_CNT);
        float*        sums     = (float*)(ws + OFF_CNT + 2048);
        unsigned int* done_all = (unsigned int*)(ws + OFF_CNT + 2064);

        hipMemsetAsync(ws + OFF_CNT, 0, 4096, stream);
        partition_edges<<<NBLK_PART, B, 0, stream>>>(row, col, attr,
                                                     pred, target, mask, v,
                                                     gcur, rec_g);
        accum_bucket<<<NB, 1024, 0, stream>>>(gcur, rec_g, v,
                                              pred, target, mask,
                                              sums, done_all, out);
    } else {
        // fallback
        float2* v    = (float2*)ws;
        float2* mv   = (float2*)(ws + (size_t)N_NODES * 8);
        float*  sums = (float*)(ws + 2ull * N_NODES * 8);
        hipMemsetAsync(mv, 0, (size_t)N_NODES * 8 + 16, stream);
        node_prep_fb<<<(N_NODES + B - 1) / B, B, 0, stream>>>(pred, target, mask, v);
        edge_scatter_fb<<<(N_EDGES + B - 1) / B, B, 0, stream>>>(row, col, attr, v, mv);
        finalize_fb<<<(N_NODES + B - 1) / B, B, 0, stream>>>(pred, target, mask, v, mv, sums);
        write_out_fb<<<1, 64, 0, stream>>>(sums, out);
    }
}

// Round 11
// 192.671 us; speedup vs baseline: 1.1109x; 1.1109x over previous
//
#include <hip/hip_runtime.h>
#include <hip/hip_fp16.h>
#include <math.h>

// Problem constants (from reference)
constexpr int N_NODES = 100000;
constexpr int N_EDGES = 3200000;
constexpr int NF      = 6;

// R11: message-in-record.  Ledger of the accum-gather campaign:
//   R5 51.2us (latency-model fit), R6/R7/R8 ILP attempts flat (VGPR pinned
//   28 x3), R9 2-blocks/CU flat -> binder is per-CU divergent-gather
//   address throughput (shared resource), R10 global_load_lds gather WRONG
//   (rule-#21 territory).  Conclusion: the gather cannot be made fast in
//   accum; move it to partition (R2 measured that cost: +9us, hidden under
//   sort latency) and stream FINISHED messages.
// Record (8B, same size as proven): { x = half2(mre,mim) bits, y = li }.
// fp16 message: rel err ~2.4e-4, |m|<~100 << 65504; summed ~32/node ->
// abs err ~1e-3 on O(1..10) outputs, bf16-compare threshold 0.12.  Safe.
// accum: pure coalesced stream + LDS atomics + LDS finalize.  No gathers,
// no flush, 4 global atomics per block.
constexpr int NB      = 256;
constexpr int NMAXB   = 392;                 // max nodes per bucket (391) padded
constexpr int CAP     = 13312;               // 13*1024; mean 12500 + 7.3 sigma
constexpr int KREC    = CAP / 1024;          // 13 records per accum thread
constexpr int TILE    = 2048;                // edges per partition block
constexpr int EPT     = TILE / 256;          // 8 edges per thread (contiguous group)
constexpr int NBLK_PART = (N_EDGES + TILE - 1) / TILE;     // 1563
constexpr int VPREP_BLOCKS = (N_NODES + 255) / 256;        // 391

__device__ __forceinline__ unsigned bucket_of(int r) {
    // floor(r*256/100000), exact for x < 2^45/11168
    return (unsigned)(((unsigned long long)((unsigned)r << 8) * 351843721ull) >> 45);
}
__device__ __forceinline__ int base_of(unsigned b) {
    return (int)((b * 100000u + 255u) >> 8);
}

// ---------------- ws layout (bytes) ----------------
constexpr size_t OFF_V    = 0;                                // float2[N_NODES]
constexpr size_t OFF_REC  = OFF_V + (size_t)N_NODES * 8;      // 800,000
constexpr size_t OFF_CNT  = OFF_REC + (size_t)NB * CAP * 8;   // +27,262,976
// counter block (zeroed by 2KB hipMemsetAsync):
//   gcur[256] at +0 (1024B), sums[3] at +1536, done_all at +1552
constexpr size_t WS_NEED  = OFF_CNT + 2048;   // ~28.1 MB (< proven-safe 42.85 MB)

__device__ __forceinline__ float2 half2u_to_f2(unsigned u) {
    __half2 h;
    *reinterpret_cast<unsigned*>(&h) = u;
    return __half22float2(h);
}

// Kernel 1: V = Vm * e^{iVa}.  Separate kernel (R2-proven ordering):
// partition gathers v[col] for ALL nodes, so v must be complete first.
__global__ __launch_bounds__(256) void node_prep(
        const float* __restrict__ pred,
        const float* __restrict__ target,
        const unsigned char* __restrict__ mask,
        float2* __restrict__ v) {
    int i = blockIdx.x * 256 + threadIdx.x;
    if (i >= N_NODES) return;
    const int b = i * NF;
    uchar2 m01 = *(const uchar2*)(mask + b);      // b=6i even -> 2-aligned
    float2 p01 = *(const float2*)(pred + b);      // byte 24i  -> 8-aligned
    float2 t01 = *(const float2*)(target + b);
    float vm = m01.x ? p01.x : t01.x;
    float va = m01.y ? p01.y : t01.y;
    float s, c;
    sincosf(va, &s, &c);
    v[i] = make_float2(vm * c, vm * s);
}

// Kernel 2: bucket-sort edges through LDS into per-bucket record chunks.
// Proven NB=256 form (51us x3 builds) + R2's gather-and-finish fold:
// Phase 4 gathers v[col] (8 independent/thread, hidden under sort latency)
// and packs the finished half2 message.  Payload stays 8 B/record.
__global__ __launch_bounds__(256) void partition_edges(
        const int* __restrict__ row, const int* __restrict__ col,
        const float2* __restrict__ attr,
        const float2* __restrict__ v,
        unsigned int* __restrict__ gcur,
        uint2* __restrict__ rec_g) {
    __shared__ unsigned int h[4][NB];       // per-wave histogram (4 KB)
    __shared__ unsigned int cur[4][NB];     // per-wave placement cursor (4 KB)
    __shared__ int wb[4][NB];               // per-wave LDS base slot (4 KB)
    __shared__ int dbase[NB];               // global_base - local_base (1 KB)
    __shared__ unsigned int wsum_s[4];      // per-wave scan totals
    __shared__ uint2 rec_s[TILE];           // staged records (bucket-sorted), 16 KB
    __shared__ unsigned char bkt_s[TILE];   // staged bucket id (2 KB)
    __shared__ int total_s;

    const int tid = threadIdx.x;
    const int w = tid >> 6;
    const int e0 = blockIdx.x * TILE;
    const int e_base = e0 + tid * EPT;          // 8 contiguous edges per thread
    const bool ok = e_base < N_EDGES;           // N_EDGES % 8 == 0

    for (int i = tid; i < 4 * NB; i += 256) {
        (&h[0][0])[i] = 0u;
        (&cur[0][0])[i] = 0u;
    }
    __syncthreads();

    // Phase 1: vectorized row loads (2 x int4) + per-wave LDS histogram
    int r[EPT];
    unsigned bk[EPT];
    if (ok) {
        int4 ra = *(const int4*)(row + e_base);
        int4 rb = *(const int4*)(row + e_base + 4);
        r[0]=ra.x; r[1]=ra.y; r[2]=ra.z; r[3]=ra.w;
        r[4]=rb.x; r[5]=rb.y; r[6]=rb.z; r[7]=rb.w;
        #pragma unroll
        for (int k = 0; k < EPT; ++k) {
            bk[k] = bucket_of(r[k]);
            atomicAdd(&h[w][bk[k]], 1u);
        }
    }
    __syncthreads();

    // Phase 2+3: totals + parallel exclusive scan + global chunk reservation
    {
        unsigned tot = h[0][tid] + h[1][tid] + h[2][tid] + h[3][tid];
        unsigned incl = tot;
        #pragma unroll
        for (int off = 1; off < 64; off <<= 1) {
            unsigned n = __shfl_up(incl, off, 64);
            if ((tid & 63) >= off) incl += n;
        }
        if ((tid & 63) == 63) wsum_s[w] = incl;
        __syncthreads();
        unsigned woff = 0;
        if (w > 0) woff += wsum_s[0];
        if (w > 1) woff += wsum_s[1];
        if (w > 2) woff += wsum_s[2];
        incl += woff;
        int lbase = (int)(incl - tot);
        unsigned t0 = h[0][tid], t1 = h[1][tid], t2 = h[2][tid];
        unsigned g = tot ? atomicAdd(&gcur[tid], tot) : 0u;
        dbase[tid] = (int)g - lbase;
        wb[0][tid] = lbase;
        wb[1][tid] = lbase + (int)t0;
        wb[2][tid] = lbase + (int)(t0 + t1);
        wb[3][tid] = lbase + (int)(t0 + t1 + t2);
        if (tid == NB - 1) total_s = (int)incl;
    }
    __syncthreads();

    // Phase 4: gather v[col] (8 independent, issued up front), compute the
    // finished message, pack { half2(mre,mim), li } into sorted LDS slots.
    if (ok) {
        int4 ca = *(const int4*)(col + e_base);
        int4 cb = *(const int4*)(col + e_base + 4);
        int c[EPT] = {ca.x, ca.y, ca.z, ca.w, cb.x, cb.y, cb.z, cb.w};
        float2 vv[EPT];
        #pragma unroll
        for (int k = 0; k < EPT; ++k) vv[k] = v[c[k]];
        float4 a0 = *(const float4*)(attr + e_base);      // edges 0,1
        float4 a1 = *(const float4*)(attr + e_base + 2);  // edges 2,3
        float4 a2 = *(const float4*)(attr + e_base + 4);  // edges 4,5
        float4 a3 = *(const float4*)(attr + e_base + 6);  // edges 6,7
        float gx[EPT] = {a0.x, a0.z, a1.x, a1.z, a2.x, a2.z, a3.x, a3.z};
        float gy[EPT] = {a0.y, a0.w, a1.y, a1.w, a2.y, a2.w, a3.y, a3.w};
        #pragma unroll
        for (int k = 0; k < EPT; ++k) {
            unsigned b = bk[k];
            unsigned li = (unsigned)(r[k] - base_of(b));   // <= 390
            int slot = wb[w][b] + (int)atomicAdd(&cur[w][b], 1u);
            // (G - iB) * conj(V) = (G*vr - B*vi) + i*(-(G*vi + B*vr))
            float mre = fmaf(gx[k], vv[k].x, -gy[k] * vv[k].y);
            float mim = -fmaf(gx[k], vv[k].y, gy[k] * vv[k].x);
            __half2 hh = __floats2half2_rn(mre, mim);
            rec_s[slot] = make_uint2(*reinterpret_cast<unsigned int*>(&hh), li);
            bkt_s[slot] = (unsigned char)b;
        }
    }
    __syncthreads();

    // Phase 5: coalesced flush in slot order (one dwordx2 store per record)
    const int total = total_s;
    for (int j = tid; j < total; j += 256) {
        int b = (int)bkt_s[j];
        int g = dbase[b] + j;
        if (g < CAP)
            rec_g[(size_t)b * CAP + g] = rec_s[j];
    }
}

// Kernel 3: one 1024-thread block per bucket, 256 blocks == 256 CUs.
// Pure coalesced stream of finished messages + LDS atomics — no gathers,
// no dependent chains.  Finalize straight from LDS (thread tid owns node
// base(b)+tid).  Global atomics: 3 returned adds + 1 done-counter/block.
__global__ __launch_bounds__(1024) void accum_bucket(
        const unsigned int* __restrict__ gcur,
        const uint2* __restrict__ rec,
        const float2* __restrict__ v,
        const float* __restrict__ pred,
        const float* __restrict__ target,
        const unsigned char* __restrict__ mask,
        float* __restrict__ sums,
        unsigned int* __restrict__ done_all,
        float* __restrict__ out) {
    __shared__ float acc_re[NMAXB];
    __shared__ float acc_im[NMAXB];
    const int tid = threadIdx.x;
    const int b = blockIdx.x;
    const int cnt = (int)min(gcur[b], (unsigned)CAP);
    if (tid < NMAXB) { acc_re[tid] = 0.f; acc_im[tid] = 0.f; }
    __syncthreads();
    const uint2* rp = rec + (size_t)b * CAP;

    #pragma unroll
    for (int k = 0; k < KREC; ++k) {
        int idx = tid + (k << 10);
        uint2 q = rp[idx];                   // unconditional: idx < CAP always
        if (idx < cnt) {
            float2 m = half2u_to_f2(q.x);
            int li = (int)q.y;
            atomicAdd(&acc_re[li], m.x);
            atomicAdd(&acc_im[li], m.y);
        }
    }
    __syncthreads();

    // ---- finalize straight from LDS: thread tid owns node base+tid ----
    const int base = base_of((unsigned)b);
    const int nb_nodes = base_of((unsigned)b + 1) - base;   // 390 or 391
    float a = 0.f, ar = 0.f, ai = 0.f;
    if (tid < nb_nodes) {
        int i = base + tid;
        float mr = acc_re[tid];
        float mi = acc_im[tid];
        const int bb = i * NF;
        uchar2 m23 = *(const uchar2*)(mask + bb + 2);   // 6i+2 even -> 2-aligned
        uchar2 m45 = *(const uchar2*)(mask + bb + 4);
        float2 p23 = *(const float2*)(pred + bb + 2);   // byte 24i+8  -> 8-aligned
        float2 p45 = *(const float2*)(pred + bb + 4);   // byte 24i+16 -> 8-aligned
        float2 t23 = *(const float2*)(target + bb + 2);
        float2 t45 = *(const float2*)(target + bb + 4);
        float pg = m23.x ? p23.x : t23.x;
        float qg = m23.y ? p23.y : t23.y;
        float pd = m45.x ? p45.x : t45.x;
        float qd = m45.y ? p45.y : t45.y;
        float2 vv2 = v[i];
        float s_re = vv2.x * mr - vv2.y * mi;
        float s_im = vv2.x * mi + vv2.y * mr;
        float dre = (pg - pd) - s_re;
        float dim = (qg - qd) - s_im;
        ar = fabsf(dre);
        ai = fabsf(dim);
        a  = sqrtf(dre * dre + dim * dim);
    }
    #pragma unroll
    for (int off = 32; off > 0; off >>= 1) {
        a  += __shfl_down(a,  off, 64);
        ar += __shfl_down(ar, off, 64);
        ai += __shfl_down(ai, off, 64);
    }
    __shared__ float red[3][16];
    int wave = tid >> 6;
    int lane = tid & 63;
    if (lane == 0) { red[0][wave] = a; red[1][wave] = ar; red[2][wave] = ai; }
    __syncthreads();
    if (tid == 0) {
        float s0 = 0.f, s1 = 0.f, s2 = 0.f;
        #pragma unroll
        for (int k = 0; k < 16; ++k) { s0 += red[0][k]; s1 += red[1][k]; s2 += red[2][k]; }
        // returned atomics: data dependency guarantees visibility before done_all
        float r0 = atomicAdd(&sums[0], s0);
        float r1 = atomicAdd(&sums[1], s1);
        float r2 = atomicAdd(&sums[2], s2);
        float chk = r0 + r1 + r2;
        if (chk == chk) {
            unsigned fin = atomicAdd(done_all, 1u);
            if (fin == (unsigned)(NB - 1)) {
                const float inv = 1.0f / (float)N_NODES;
                float t0 = atomicAdd(&sums[0], 0.f);   // coherent readback
                float t1 = atomicAdd(&sums[1], 0.f);
                float t2 = atomicAdd(&sums[2], 0.f);
                __hip_atomic_store(&out[0], t0 * inv, __ATOMIC_RELAXED, __HIP_MEMORY_SCOPE_AGENT);
                __hip_atomic_store(&out[1], t1 * inv, __ATOMIC_RELAXED, __HIP_MEMORY_SCOPE_AGENT);
                __hip_atomic_store(&out[2], t2 * inv, __ATOMIC_RELAXED, __HIP_MEMORY_SCOPE_AGENT);
            }
        }
    }
}

// ---------------- fallback (plain atomic path, if ws too small) ------------
__global__ void node_prep_fb(const float* __restrict__ pred,
                             const float* __restrict__ target,
                             const unsigned char* __restrict__ mask,
                             float2* __restrict__ v) {
    int i = blockIdx.x * blockDim.x + threadIdx.x;
    if (i >= N_NODES) return;
    const int b = i * NF;
    float vm = mask[b + 0] ? pred[b + 0] : target[b + 0];
    float va = mask[b + 1] ? pred[b + 1] : target[b + 1];
    float s, c;
    sincosf(va, &s, &c);
    v[i] = make_float2(vm * c, vm * s);
}

__global__ void edge_scatter_fb(const int* __restrict__ row,
                                const int* __restrict__ col,
                                const float2* __restrict__ attr,
                                const float2* __restrict__ v,
                                float2* __restrict__ mv) {
    int e = blockIdx.x * blockDim.x + threadIdx.x;
    if (e >= N_EDGES) return;
    int r = row[e];
    int c = col[e];
    float2 gb = attr[e];
    float2 vv = v[c];
    float mre = fmaf(gb.x, vv.x, -gb.y * vv.y);
    float mim = -fmaf(gb.x, vv.y, gb.y * vv.x);
    atomicAdd(&mv[r].x, mre);
    atomicAdd(&mv[r].y, mim);
}

__global__ void finalize_fb(const float* __restrict__ pred,
                            const float* __restrict__ target,
                            const unsigned char* __restrict__ mask,
                            const float2* __restrict__ v,
                            const float2* __restrict__ mv,
                            float* __restrict__ sums) {
    int i = blockIdx.x * blockDim.x + threadIdx.x;
    float a = 0.f, ar = 0.f, ai = 0.f;
    if (i < N_NODES) {
        const int b = i * NF;
        float pg = mask[b + 2] ? pred[b + 2] : target[b + 2];
        float qg = mask[b + 3] ? pred[b + 3] : target[b + 3];
        float pd = mask[b + 4] ? pred[b + 4] : target[b + 4];
        float qd = mask[b + 5] ? pred[b + 5] : target[b + 5];
        float netP = pg - pd;
        float netQ = qg - qd;
        float2 vv = v[i];
        float2 m = mv[i];
        float s_re = vv.x * m.x - vv.y * m.y;
        float s_im = vv.x * m.y + vv.y * m.x;
        float dre = netP - s_re;
        float dim = netQ - s_im;
        ar = fabsf(dre);
        ai = fabsf(dim);
        a  = sqrtf(dre * dre + dim * dim);
    }
    #pragma unroll
    for (int off = 32; off > 0; off >>= 1) {
        a  += __shfl_down(a,  off, 64);
        ar += __shfl_down(ar, off, 64);
        ai += __shfl_down(ai, off, 64);
    }
    __shared__ float red[3][4];
    int wave = threadIdx.x >> 6;
    int lane = threadIdx.x & 63;
    if (lane == 0) { red[0][wave] = a; red[1][wave] = ar; red[2][wave] = ai; }
    __syncthreads();
    if (threadIdx.x == 0) {
        atomicAdd(&sums[0], red[0][0] + red[0][1] + red[0][2] + red[0][3]);
        atomicAdd(&sums[1], red[1][0] + red[1][1] + red[1][2] + red[1][3]);
        atomicAdd(&sums[2], red[2][0] + red[2][1] + red[2][2] + red[2][3]);
    }
}

__global__ void write_out_fb(const float* __restrict__ sums, float* __restrict__ out) {
    if (threadIdx.x == 0 && blockIdx.x == 0) {
        const float inv = 1.0f / (float)N_NODES;
        out[0] = sums[0] * inv;
        out[1] = sums[1] * inv;
        out[2] = sums[2] * inv;
    }
}

extern "C" void kernel_launch(void* const* d_in, const int* in_sizes, int n_in,
                              void* d_out, int out_size, void* d_ws, size_t ws_size,
                              hipStream_t stream) {
    const float*         pred   = (const float*)d_in[0];
    const float*         target = (const float*)d_in[1];
    const int*           eidx   = (const int*)d_in[2];      // (2, N_EDGES)
    const float2*        attr   = (const float2*)d_in[3];   // (N_EDGES, 2)
    const unsigned char* mask   = (const unsigned char*)d_in[4];
    float* out = (float*)d_out;

    const int* row = eidx;             // edge_index[0] = src
    const int* col = eidx + N_EDGES;   // edge_index[1] = dst

    char* ws = (char*)d_ws;
    const int B = 256;

    if (ws_size >= WS_NEED) {
        float2*       v        = (float2*)(ws + OFF_V);
        uint2*        rec_g    = (uint2*)(ws + OFF_REC);
        unsigned int* gcur     = (unsigned int*)(ws + OFF_CNT);
        float*        sums     = (float*)(ws + OFF_CNT + 1536);
        unsigned int* done_all = (unsigned int*)(ws + OFF_CNT + 1552);

        hipMemsetAsync(ws + OFF_CNT, 0, 2048, stream);
        node_prep<<<VPREP_BLOCKS, B, 0, stream>>>(pred, target, mask, v);
        partition_edges<<<NBLK_PART, B, 0, stream>>>(row, col, attr, v,
                                                     gcur, rec_g);
        accum_bucket<<<NB, 1024, 0, stream>>>(gcur, rec_g, v,
                                              pred, target, mask,
                                              sums, done_all, out);
    } else {
        // fallback
        float2* v    = (float2*)ws;
        float2* mv   = (float2*)(ws + (size_t)N_NODES * 8);
        float*  sums = (float*)(ws + 2ull * N_NODES * 8);
        hipMemsetAsync(mv, 0, (size_t)N_NODES * 8 + 16, stream);
        node_prep_fb<<<(N_NODES + B - 1) / B, B, 0, stream>>>(pred, target, mask, v);
        edge_scatter_fb<<<(N_EDGES + B - 1) / B, B, 0, stream>>>(row, col, attr, v, mv);
        finalize_fb<<<(N_NODES + B - 1) / B, B, 0, stream>>>(pred, target, mask, v, mv, sums);
        write_out_fb<<<1, 64, 0, stream>>>(sums, out);
    }
}

// Round 12
// 183.009 us; speedup vs baseline: 1.1695x; 1.0528x over previous
//
#include <hip/hip_runtime.h>
#include <hip/hip_fp16.h>
#include <math.h>

// Problem constants (from reference)
constexpr int N_NODES = 100000;
constexpr int N_EDGES = 3200000;
constexpr int NF      = 6;

// FINAL (R12 = R5 revert): best harness-verified configuration, 178.1 us.
// Session ledger:
//   R0-R2: NSLICE split + flush variants: 183-196 us (flush atomics bind).
//   R3:    direct global atomics: 431 us (measured: coherent-point f32
//          atomic = 32B HBM write-through, ~20 G/s -> never again).
//   R4:    bucket-per-block, NB=98: accum 93.6 us @ 38% CU coverage.
//   R5:    NB=256 == CU count: 178.1 us (THIS KERNEL).  accum fit:
//          T = ~24us fixed + cnt/482-per-us-per-CU.
//   R6-R8: deep-load-queue ILP x3 -> compiler sank loads every time
//          (VGPR pinned 28; liveness cannot be forced by ordering tools).
//   R9:    NB=512 (2 blocks/CU TLP): partition regressed (write amp),
//          accum flat -> binder is per-CU divergent-gather addr throughput.
//   R10:   global_load_lds per-lane gather: WRONG RESULTS (rule #21).
//   R11:   message-in-record (gather moved to partition): sum flat
//          (+9 partition, -? accum, +8 node_prep = 192.7).
// Conclusion: structural plateau for this decomposition at HIP source
// level; dominant residuals are fixed per-launch costs (~24us/kernel) and
// harness overhead (~75us), not any counter-visible pipe.
constexpr int NB      = 256;
constexpr int NMAXB   = 392;                 // max nodes per bucket (391) padded
constexpr int CAP     = 13312;               // 13*1024; mean 12500 + 7.3 sigma
constexpr int TILE    = 2048;                // edges per partition block
constexpr int EPT     = TILE / 256;          // 8 edges per thread (contiguous group)
constexpr int NBLK_PART = (N_EDGES + TILE - 1) / TILE;     // 1563
constexpr int VPREP_BLOCKS = (N_NODES + 255) / 256;        // 391

__device__ __forceinline__ unsigned bucket_of(int r) {
    // floor(r*256/100000), exact for x < 2^45/11168
    return (unsigned)(((unsigned long long)((unsigned)r << 8) * 351843721ull) >> 45);
}
__device__ __forceinline__ int base_of(unsigned b) {
    return (int)((b * 100000u + 255u) >> 8);
}

// ---------------- ws layout (bytes) ----------------
constexpr size_t OFF_V    = 0;                                // float2[N_NODES]
constexpr size_t OFF_REC  = OFF_V + (size_t)N_NODES * 8;      // 800,000
constexpr size_t OFF_CNT  = OFF_REC + (size_t)NB * CAP * 8;   // +27,262,976
// counter block (zeroed by 2KB hipMemsetAsync):
//   gcur[256] at +0 (1024B), sums[3] at +1536, done_all at +1552
constexpr size_t WS_NEED  = OFF_CNT + 2048;   // ~28.1 MB (< proven-safe 42.85 MB)

__device__ __forceinline__ float2 half2u_to_f2(unsigned u) {
    __half2 h;
    *reinterpret_cast<unsigned*>(&h) = u;
    return __half22float2(h);
}

// Bucket-sort edges through LDS into per-bucket record chunks (proven form:
// 8 B packed record { col | li<<17, half2 attr }; li<=390 fits bits 17..25).
// Folds node_prep (V = Vm*e^{iVa}) into the first 391 blocks — v is only
// consumed by the NEXT kernel, so no intra-kernel ordering needed.
__global__ __launch_bounds__(256) void partition_edges(
        const int* __restrict__ row, const int* __restrict__ col,
        const float2* __restrict__ attr,
        const float* __restrict__ pred, const float* __restrict__ target,
        const unsigned char* __restrict__ mask,
        float2* __restrict__ v_out,
        unsigned int* __restrict__ gcur,
        uint2* __restrict__ rec_g) {
    __shared__ unsigned int h[4][NB];       // per-wave histogram (4 KB)
    __shared__ unsigned int cur[4][NB];     // per-wave placement cursor (4 KB)
    __shared__ int wb[4][NB];               // per-wave LDS base slot (4 KB)
    __shared__ int dbase[NB];               // global_base - local_base (1 KB)
    __shared__ unsigned int wsum_s[4];      // per-wave scan totals
    __shared__ uint2 rec_s[TILE];           // staged records (bucket-sorted), 16 KB
    __shared__ unsigned char bkt_s[TILE];   // staged bucket id (2 KB)
    __shared__ int total_s;

    const int tid = threadIdx.x;
    const int w = tid >> 6;
    const int e0 = blockIdx.x * TILE;
    const int e_base = e0 + tid * EPT;          // 8 contiguous edges per thread
    const bool ok = e_base < N_EDGES;           // N_EDGES % 8 == 0

    // folded node_prep (no LDS use; overlaps with everything)
    if (blockIdx.x < VPREP_BLOCKS) {
        int i = blockIdx.x * 256 + tid;
        if (i < N_NODES) {
            const int bb = i * NF;
            float vm = mask[bb + 0] ? pred[bb + 0] : target[bb + 0];
            float va = mask[bb + 1] ? pred[bb + 1] : target[bb + 1];
            float sn, cs;
            sincosf(va, &sn, &cs);
            v_out[i] = make_float2(vm * cs, vm * sn);
        }
    }

    for (int i = tid; i < 4 * NB; i += 256) {
        (&h[0][0])[i] = 0u;
        (&cur[0][0])[i] = 0u;
    }
    __syncthreads();

    // Phase 1: vectorized row loads (2 x int4) + per-wave LDS histogram
    int r[EPT];
    unsigned bk[EPT];
    if (ok) {
        int4 ra = *(const int4*)(row + e_base);
        int4 rb = *(const int4*)(row + e_base + 4);
        r[0]=ra.x; r[1]=ra.y; r[2]=ra.z; r[3]=ra.w;
        r[4]=rb.x; r[5]=rb.y; r[6]=rb.z; r[7]=rb.w;
        #pragma unroll
        for (int k = 0; k < EPT; ++k) {
            bk[k] = bucket_of(r[k]);
            atomicAdd(&h[w][bk[k]], 1u);
        }
    }
    __syncthreads();

    // Phase 2+3: totals + parallel exclusive scan (shfl intra-wave + wave
    // offsets) + global chunk reservation.  tid == bucket id (NB == 256).
    {
        unsigned tot = h[0][tid] + h[1][tid] + h[2][tid] + h[3][tid];
        unsigned incl = tot;
        #pragma unroll
        for (int off = 1; off < 64; off <<= 1) {
            unsigned n = __shfl_up(incl, off, 64);
            if ((tid & 63) >= off) incl += n;
        }
        if ((tid & 63) == 63) wsum_s[w] = incl;
        __syncthreads();
        unsigned woff = 0;
        if (w > 0) woff += wsum_s[0];
        if (w > 1) woff += wsum_s[1];
        if (w > 2) woff += wsum_s[2];
        incl += woff;
        int lbase = (int)(incl - tot);
        unsigned t0 = h[0][tid], t1 = h[1][tid], t2 = h[2][tid];
        unsigned g = tot ? atomicAdd(&gcur[tid], tot) : 0u;
        dbase[tid] = (int)g - lbase;
        wb[0][tid] = lbase;
        wb[1][tid] = lbase + (int)t0;
        wb[2][tid] = lbase + (int)(t0 + t1);
        wb[3][tid] = lbase + (int)(t0 + t1 + t2);
        if (tid == NB - 1) total_s = (int)incl;
    }
    __syncthreads();

    // Phase 4: pack records (col|li<<17, half2 attr), place into sorted LDS slots
    if (ok) {
        int4 ca = *(const int4*)(col + e_base);
        int4 cb = *(const int4*)(col + e_base + 4);
        int c[EPT] = {ca.x, ca.y, ca.z, ca.w, cb.x, cb.y, cb.z, cb.w};
        float4 a0 = *(const float4*)(attr + e_base);      // edges 0,1
        float4 a1 = *(const float4*)(attr + e_base + 2);  // edges 2,3
        float4 a2 = *(const float4*)(attr + e_base + 4);  // edges 4,5
        float4 a3 = *(const float4*)(attr + e_base + 6);  // edges 6,7
        float gx[EPT] = {a0.x, a0.z, a1.x, a1.z, a2.x, a2.z, a3.x, a3.z};
        float gy[EPT] = {a0.y, a0.w, a1.y, a1.w, a2.y, a2.w, a3.y, a3.w};
        #pragma unroll
        for (int k = 0; k < EPT; ++k) {
            unsigned b = bk[k];
            unsigned li = (unsigned)(r[k] - base_of(b));   // <= 390
            int slot = wb[w][b] + (int)atomicAdd(&cur[w][b], 1u);
            __half2 hh = __floats2half2_rn(gx[k], gy[k]);
            rec_s[slot] = make_uint2((unsigned)c[k] | (li << 17),
                                     *reinterpret_cast<unsigned int*>(&hh));
            bkt_s[slot] = (unsigned char)b;                // b <= 255 fits exactly
        }
    }
    __syncthreads();

    // Phase 5: coalesced flush in slot order (one dwordx2 store per record)
    const int total = total_s;
    for (int j = tid; j < total; j += 256) {
        int b = (int)bkt_s[j];
        int g = dbase[b] + j;
        if (g < CAP)
            rec_g[(size_t)b * CAP + g] = rec_s[j];
    }
}

// One 1024-thread block per bucket, 256 blocks == 256 CUs (R4 structure at
// full device coverage).  Stream the bucket's ~12.5k records (4-wide, ~3
// iterations/thread, 16 waves), LDS-accumulate, finalize straight from LDS
// (thread tid owns node base(b)+tid).  Global atomics: 3 returned adds +
// 1 done-counter per block — nothing else.
__global__ __launch_bounds__(1024) void accum_bucket(
        const unsigned int* __restrict__ gcur,
        const uint2* __restrict__ rec,
        const float2* __restrict__ v,
        const float* __restrict__ pred,
        const float* __restrict__ target,
        const unsigned char* __restrict__ mask,
        float* __restrict__ sums,
        unsigned int* __restrict__ done_all,
        float* __restrict__ out) {
    __shared__ float acc_re[NMAXB];
    __shared__ float acc_im[NMAXB];
    const int tid = threadIdx.x;
    const int b = blockIdx.x;
    const int cnt = (int)min(gcur[b], (unsigned)CAP);
    if (tid < NMAXB) { acc_re[tid] = 0.f; acc_im[tid] = 0.f; }
    __syncthreads();
    const uint2* rp = rec + (size_t)b * CAP;
    int j = 4 * tid;
    for (; j + 3 < cnt; j += 4096) {
        uint4 q0 = *(const uint4*)(rp + j);       // records j, j+1
        uint4 q1 = *(const uint4*)(rp + j + 2);   // records j+2, j+3
        int c0 = (int)(q0.x & 0x1FFFFu), li0 = (int)(q0.x >> 17);
        int c1 = (int)(q0.z & 0x1FFFFu), li1 = (int)(q0.z >> 17);
        int c2 = (int)(q1.x & 0x1FFFFu), li2 = (int)(q1.x >> 17);
        int c3 = (int)(q1.z & 0x1FFFFu), li3 = (int)(q1.z >> 17);
        float2 vv0 = v[c0];
        float2 vv1 = v[c1];
        float2 vv2 = v[c2];
        float2 vv3 = v[c3];
        float2 gb0 = half2u_to_f2(q0.y);
        float2 gb1 = half2u_to_f2(q0.w);
        float2 gb2 = half2u_to_f2(q1.y);
        float2 gb3 = half2u_to_f2(q1.w);
        // (G - iB) * conj(V) = (G*vr - B*vi) + i*(-(G*vi + B*vr))
        atomicAdd(&acc_re[li0], fmaf(gb0.x, vv0.x, -gb0.y * vv0.y));
        atomicAdd(&acc_im[li0], -fmaf(gb0.x, vv0.y, gb0.y * vv0.x));
        atomicAdd(&acc_re[li1], fmaf(gb1.x, vv1.x, -gb1.y * vv1.y));
        atomicAdd(&acc_im[li1], -fmaf(gb1.x, vv1.y, gb1.y * vv1.x));
        atomicAdd(&acc_re[li2], fmaf(gb2.x, vv2.x, -gb2.y * vv2.y));
        atomicAdd(&acc_im[li2], -fmaf(gb2.x, vv2.y, gb2.y * vv2.x));
        atomicAdd(&acc_re[li3], fmaf(gb3.x, vv3.x, -gb3.y * vv3.y));
        atomicAdd(&acc_im[li3], -fmaf(gb3.x, vv3.y, gb3.y * vv3.x));
    }
    for (; j < cnt; ++j) {                        // partial last group (<4)
        uint2 q = rp[j];
        int c0 = (int)(q.x & 0x1FFFFu), li0 = (int)(q.x >> 17);
        float2 vv0 = v[c0];
        float2 gb0 = half2u_to_f2(q.y);
        atomicAdd(&acc_re[li0], fmaf(gb0.x, vv0.x, -gb0.y * vv0.y));
        atomicAdd(&acc_im[li0], -fmaf(gb0.x, vv0.y, gb0.y * vv0.x));
    }
    __syncthreads();

    // ---- finalize straight from LDS: thread tid owns node base+tid ----
    const int base = base_of((unsigned)b);
    const int nb_nodes = base_of((unsigned)b + 1) - base;   // 390 or 391
    float a = 0.f, ar = 0.f, ai = 0.f;
    if (tid < nb_nodes) {
        int i = base + tid;
        float mr = acc_re[tid];
        float mi = acc_im[tid];
        const int bb = i * NF;
        uchar2 m23 = *(const uchar2*)(mask + bb + 2);   // 6i+2 even -> 2-aligned
        uchar2 m45 = *(const uchar2*)(mask + bb + 4);
        float2 p23 = *(const float2*)(pred + bb + 2);   // byte 24i+8  -> 8-aligned
        float2 p45 = *(const float2*)(pred + bb + 4);   // byte 24i+16 -> 8-aligned
        float2 t23 = *(const float2*)(target + bb + 2);
        float2 t45 = *(const float2*)(target + bb + 4);
        float pg = m23.x ? p23.x : t23.x;
        float qg = m23.y ? p23.y : t23.y;
        float pd = m45.x ? p45.x : t45.x;
        float qd = m45.y ? p45.y : t45.y;
        float2 vv = v[i];
        float s_re = vv.x * mr - vv.y * mi;
        float s_im = vv.x * mi + vv.y * mr;
        float dre = (pg - pd) - s_re;
        float dim = (qg - qd) - s_im;
        ar = fabsf(dre);
        ai = fabsf(dim);
        a  = sqrtf(dre * dre + dim * dim);
    }
    #pragma unroll
    for (int off = 32; off > 0; off >>= 1) {
        a  += __shfl_down(a,  off, 64);
        ar += __shfl_down(ar, off, 64);
        ai += __shfl_down(ai, off, 64);
    }
    __shared__ float red[3][16];
    int wave = tid >> 6;
    int lane = tid & 63;
    if (lane == 0) { red[0][wave] = a; red[1][wave] = ar; red[2][wave] = ai; }
    __syncthreads();
    if (tid == 0) {
        float s0 = 0.f, s1 = 0.f, s2 = 0.f;
        #pragma unroll
        for (int k = 0; k < 16; ++k) { s0 += red[0][k]; s1 += red[1][k]; s2 += red[2][k]; }
        // returned atomics: data dependency guarantees visibility before done_all
        float r0 = atomicAdd(&sums[0], s0);
        float r1 = atomicAdd(&sums[1], s1);
        float r2 = atomicAdd(&sums[2], s2);
        float chk = r0 + r1 + r2;
        if (chk == chk) {
            unsigned fin = atomicAdd(done_all, 1u);
            if (fin == (unsigned)(NB - 1)) {
                const float inv = 1.0f / (float)N_NODES;
                float t0 = atomicAdd(&sums[0], 0.f);   // coherent readback
                float t1 = atomicAdd(&sums[1], 0.f);
                float t2 = atomicAdd(&sums[2], 0.f);
                __hip_atomic_store(&out[0], t0 * inv, __ATOMIC_RELAXED, __HIP_MEMORY_SCOPE_AGENT);
                __hip_atomic_store(&out[1], t1 * inv, __ATOMIC_RELAXED, __HIP_MEMORY_SCOPE_AGENT);
                __hip_atomic_store(&out[2], t2 * inv, __ATOMIC_RELAXED, __HIP_MEMORY_SCOPE_AGENT);
            }
        }
    }
}

// ---------------- fallback (plain atomic path, if ws too small) ------------
__global__ void node_prep_fb(const float* __restrict__ pred,
                             const float* __restrict__ target,
                             const unsigned char* __restrict__ mask,
                             float2* __restrict__ v) {
    int i = blockIdx.x * blockDim.x + threadIdx.x;
    if (i >= N_NODES) return;
    const int b = i * NF;
    float vm = mask[b + 0] ? pred[b + 0] : target[b + 0];
    float va = mask[b + 1] ? pred[b + 1] : target[b + 1];
    float s, c;
    sincosf(va, &s, &c);
    v[i] = make_float2(vm * c, vm * s);
}

__global__ void edge_scatter_fb(const int* __restrict__ row,
                                const int* __restrict__ col,
                                const float2* __restrict__ attr,
                                const float2* __restrict__ v,
                                float2* __restrict__ mv) {
    int e = blockIdx.x * blockDim.x + threadIdx.x;
    if (e >= N_EDGES) return;
    int r = row[e];
    int c = col[e];
    float2 gb = attr[e];
    float2 vv = v[c];
    float mre = fmaf(gb.x, vv.x, -gb.y * vv.y);
    float mim = -fmaf(gb.x, vv.y, gb.y * vv.x);
    atomicAdd(&mv[r].x, mre);
    atomicAdd(&mv[r].y, mim);
}

__global__ void finalize_fb(const float* __restrict__ pred,
                            const float* __restrict__ target,
                            const unsigned char* __restrict__ mask,
                            const float2* __restrict__ v,
                            const float2* __restrict__ mv,
                            float* __restrict__ sums) {
    int i = blockIdx.x * blockDim.x + threadIdx.x;
    float a = 0.f, ar = 0.f, ai = 0.f;
    if (i < N_NODES) {
        const int b = i * NF;
        float pg = mask[b + 2] ? pred[b + 2] : target[b + 2];
        float qg = mask[b + 3] ? pred[b + 3] : target[b + 3];
        float pd = mask[b + 4] ? pred[b + 4] : target[b + 4];
        float qd = mask[b + 5] ? pred[b + 5] : target[b + 5];
        float netP = pg - pd;
        float netQ = qg - qd;
        float2 vv = v[i];
        float2 m = mv[i];
        float s_re = vv.x * m.x - vv.y * m.y;
        float s_im = vv.x * m.y + vv.y * m.x;
        float dre = netP - s_re;
        float dim = netQ - s_im;
        ar = fabsf(dre);
        ai = fabsf(dim);
        a  = sqrtf(dre * dre + dim * dim);
    }
    #pragma unroll
    for (int off = 32; off > 0; off >>= 1) {
        a  += __shfl_down(a,  off, 64);
        ar += __shfl_down(ar, off, 64);
        ai += __shfl_down(ai, off, 64);
    }
    __shared__ float red[3][4];
    int wave = threadIdx.x >> 6;
    int lane = threadIdx.x & 63;
    if (lane == 0) { red[0][wave] = a; red[1][wave] = ar; red[2][wave] = ai; }
    __syncthreads();
    if (threadIdx.x == 0) {
        atomicAdd(&sums[0], red[0][0] + red[0][1] + red[0][2] + red[0][3]);
        atomicAdd(&sums[1], red[1][0] + red[1][1] + red[1][2] + red[1][3]);
        atomicAdd(&sums[2], red[2][0] + red[2][1] + red[2][2] + red[2][3]);
    }
}

__global__ void write_out_fb(const float* __restrict__ sums, float* __restrict__ out) {
    if (threadIdx.x == 0 && blockIdx.x == 0) {
        const float inv = 1.0f / (float)N_NODES;
        out[0] = sums[0] * inv;
        out[1] = sums[1] * inv;
        out[2] = sums[2] * inv;
    }
}

extern "C" void kernel_launch(void* const* d_in, const int* in_sizes, int n_in,
                              void* d_out, int out_size, void* d_ws, size_t ws_size,
                              hipStream_t stream) {
    const float*         pred   = (const float*)d_in[0];
    const float*         target = (const float*)d_in[1];
    const int*           eidx   = (const int*)d_in[2];      // (2, N_EDGES)
    const float2*        attr   = (const float2*)d_in[3];   // (N_EDGES, 2)
    const unsigned char* mask   = (const unsigned char*)d_in[4];
    float* out = (float*)d_out;

    const int* row = eidx;             // edge_index[0] = src
    const int* col = eidx + N_EDGES;   // edge_index[1] = dst

    char* ws = (char*)d_ws;
    const int B = 256;

    if (ws_size >= WS_NEED) {
        float2*       v        = (float2*)(ws + OFF_V);
        uint2*        rec_g    = (uint2*)(ws + OFF_REC);
        unsigned int* gcur     = (unsigned int*)(ws + OFF_CNT);
        float*        sums     = (float*)(ws + OFF_CNT + 1536);
        unsigned int* done_all = (unsigned int*)(ws + OFF_CNT + 1552);

        hipMemsetAsync(ws + OFF_CNT, 0, 2048, stream);
        partition_edges<<<NBLK_PART, B, 0, stream>>>(row, col, attr,
                                                     pred, target, mask, v,
                                                     gcur, rec_g);
        accum_bucket<<<NB, 1024, 0, stream>>>(gcur, rec_g, v,
                                              pred, target, mask,
                                              sums, done_all, out);
    } else {
        // fallback
        float2* v    = (float2*)ws;
        float2* mv   = (float2*)(ws + (size_t)N_NODES * 8);
        float*  sums = (float*)(ws + 2ull * N_NODES * 8);
        hipMemsetAsync(mv, 0, (size_t)N_NODES * 8 + 16, stream);
        node_prep_fb<<<(N_NODES + B - 1) / B, B, 0, stream>>>(pred, target, mask, v);
        edge_scatter_fb<<<(N_EDGES + B - 1) / B, B, 0, stream>>>(row, col, attr, v, mv);
        finalize_fb<<<(N_NODES + B - 1) / B, B, 0, stream>>>(pred, target, mask, v, mv, sums);
        write_out_fb<<<1, 64, 0, stream>>>(sums, out);
    }
}